// Round 14
// baseline (458.510 us; speedup 1.0000x reference)
//
#include <hip/hip_runtime.h>
#include <stdint.h>

// GraphSAGE MI355X — round 12: fused cone kernel, SPLIT-K layer-1 for 26 KB LDS
// -> 6 blocks/CU. Block b owns output rows 4b..4b+3. Cone: h1[40b..40b+39],
// h0[4b..4b+3], h2[400b..400b+399].
//   phaseA : lAh[48][256] = mean-halves  (r<40: mean10 h2 [NT]; 40-43: mean10 h1;
//            44-47 zero)
//   passB  : acc += lAh @ W1t[:,256:512]^T     (K=256..511)
//   phaseC : lAh[48][256] = self-halves  (r<40: h1; 40-43: h0; 44-47 zero)
//   passD  : acc += lAh @ W1t[:,0:256]^T       (K=0..255)
//   epilog : relu -> bf16 -> lNH[48][256] (overlays lAh)
//   phaseE : mnh[4][256] = mean10(lNH rows 0..39)
//   layer2 : A row an: k<256 from lNH[40+an], k>=256 from mnh[an] -> f32 out
// LDS = 24 KB + 2 KB = 26624 B -> 6 blocks/CU (24 waves). NT loads on h2.

typedef unsigned short u16;
typedef __attribute__((ext_vector_type(4))) float f32x4;
typedef __attribute__((ext_vector_type(8))) short s16x8;
typedef __attribute__((ext_vector_type(4))) unsigned short u16x4;

__device__ inline u16 f2bf(float x) {
    union { float f; uint32_t u; } v; v.f = x;
    uint32_t b = v.u;
    b += 0x7FFFu + ((b >> 16) & 1u);   // round-to-nearest-even
    return (u16)(b >> 16);
}
__device__ inline float bf2f(u16 u) {
    union { uint32_t u; float f; } v; v.u = ((uint32_t)u) << 16;
    return v.f;
}

// Transposed bf16 weight build: dst[n][koff+k] = f2bf(src[k][n]), 64x64 tiles.
__global__ __launch_bounds__(256) void conv_w2t(const float* __restrict__ w1s,
                                                const float* __restrict__ w1n,
                                                const float* __restrict__ w2s,
                                                const float* __restrict__ w2n,
                                                u16* __restrict__ W1t,
                                                u16* __restrict__ W2t) {
    __shared__ u16 t[64][66];
    const int b = blockIdx.x;
    const int mat = b >> 4;
    const int tk = ((b >> 2) & 3) * 64;
    const int tn = (b & 3) * 64;
    const float* src = (mat == 0) ? w1s : (mat == 1) ? w1n : (mat == 2) ? w2s : w2n;
    u16* dst = (mat < 2) ? W1t : W2t;
    const int koff = (mat & 1) * 256;
    const int tid = threadIdx.x;
    const int li = tid >> 6, ln = tid & 63;
    #pragma unroll
    for (int p = 0; p < 16; ++p) {
        int k = p * 4 + li;
        t[k][ln] = f2bf(src[(size_t)(tk + k) * 256 + tn + ln]);
    }
    __syncthreads();
    #pragma unroll
    for (int p = 0; p < 16; ++p) {
        int n = p * 4 + li;
        dst[(size_t)(tn + n) * 512 + koff + tk + ln] = t[ln][n];
    }
}

// ---- swizzled 256-u16-row LDS tile (512 B row = 32 16B-chunks; phys=chunk^(r&7))
__device__ inline void st256_4(u16* t, int r, int c, u16x4 v) {     // 8B, c mult 4
    int byte = c * 2, chunk = byte >> 4, off = byte & 15;
    *(u16x4*)((char*)t + (size_t)r * 512 + ((chunk ^ (r & 7)) * 16) + off) = v;
}
__device__ inline void st256_1(u16* t, int r, int c, u16 v) {       // 2B
    int byte = c * 2, chunk = byte >> 4, off = byte & 15;
    *(u16*)((char*)t + (size_t)r * 512 + ((chunk ^ (r & 7)) * 16) + off) = v;
}
__device__ inline u16x4 ld256_4(const u16* t, int r, int c) {       // 8B, c mult 4
    int byte = c * 2, chunk = byte >> 4, off = byte & 15;
    return *(const u16x4*)((const char*)t + (size_t)r * 512 + ((chunk ^ (r & 7)) * 16) + off);
}
__device__ inline s16x8 ld256_8(const u16* t, int r, int k) {       // 16B, k mult 8
    int chunk = (k * 2) >> 4;
    return *(const s16x8*)((const char*)t + (size_t)r * 512 + ((chunk ^ (r & 7)) * 16));
}

#define LAH_OFF 0        // lAh / lNH overlay: 48 rows x 512 B = 24576
#define MNH_OFF 24576    // mnh: 4 rows x 512 B = 2048
#define K1_LDS  26624

__global__ __launch_bounds__(256, 6) void sage_fused(const float* __restrict__ h0,
                                                     const float* __restrict__ h1,
                                                     const float* __restrict__ h2,
                                                     const u16* __restrict__ W1t,
                                                     const u16* __restrict__ W2t,
                                                     float* __restrict__ out) {
    extern __shared__ __align__(16) char smem[];
    u16* lAh = (u16*)(smem + LAH_OFF);    // [48][256], also lNH after overlay
    u16* mnh = (u16*)(smem + MNH_OFF);    // [4][256]

    const int b = blockIdx.x;
    const int tid = threadIdx.x;
    const int lane = tid & 63;
    const int w = tid >> 6;
    const int an = lane & 15;
    const int ak = (lane >> 4) * 8;

    // ---- phase A: mean halves (h2 stream via NT; hop-0 means from h1)
    #pragma unroll
    for (int p = 0; p < 12; ++p) {
        int task = p * 256 + tid;             // 48 rows x 64 quads
        int r = task >> 6;
        int c4 = (task & 63) * 4;
        u16x4 mb = {0, 0, 0, 0};
        if (r < 40) {
            const float* np = h2 + (size_t)(400 * b + 10 * r) * 256 + c4;
            f32x4 a = {0.f, 0.f, 0.f, 0.f};
            #pragma unroll
            for (int j = 0; j < 10; ++j)
                a += __builtin_nontemporal_load((const f32x4*)(np + (size_t)j * 256));
            #pragma unroll
            for (int i = 0; i < 4; ++i) mb[i] = f2bf(a[i] * 0.1f);
        } else if (r < 44) {
            const float* np = h1 + (size_t)(40 * b + 10 * (r - 40)) * 256 + c4;
            f32x4 a = {0.f, 0.f, 0.f, 0.f};
            #pragma unroll
            for (int j = 0; j < 10; ++j)
                a += *(const f32x4*)(np + (size_t)j * 256);
            #pragma unroll
            for (int i = 0; i < 4; ++i) mb[i] = f2bf(a[i] * 0.1f);
        }
        st256_4(lAh, r, c4, mb);
    }
    __syncthreads();

    // ---- pass B: acc += lAh @ W1t[:,256:512]^T
    f32x4 acc[3][4] = {};
    const u16* bp[4];
    #pragma unroll
    for (int nn = 0; nn < 4; ++nn)
        bp[nn] = W1t + (size_t)(w * 64 + nn * 16 + an) * 512 + ak;
    #pragma unroll
    for (int kt = 0; kt < 4; ++kt) {
        const int kbase = kt * 64;
        s16x8 bF[2][4];
        #pragma unroll
        for (int ks = 0; ks < 2; ++ks)
            #pragma unroll
            for (int nn = 0; nn < 4; ++nn)
                bF[ks][nn] = *(const s16x8*)(bp[nn] + 256 + kbase + ks * 32);
        #pragma unroll
        for (int ks = 0; ks < 2; ++ks) {
            s16x8 aF[3];
            #pragma unroll
            for (int m = 0; m < 3; ++m)
                aF[m] = ld256_8(lAh, m * 16 + an, kbase + ks * 32 + ak);
            #pragma unroll
            for (int m = 0; m < 3; ++m)
                #pragma unroll
                for (int nn = 0; nn < 4; ++nn)
                    acc[m][nn] = __builtin_amdgcn_mfma_f32_16x16x32_bf16(aF[m], bF[ks][nn], acc[m][nn], 0, 0, 0);
        }
    }
    __syncthreads();

    // ---- phase C: self halves
    #pragma unroll
    for (int p = 0; p < 12; ++p) {
        int task = p * 256 + tid;
        int r = task >> 6;
        int c4 = (task & 63) * 4;
        u16x4 sb = {0, 0, 0, 0};
        if (r < 44) {
            const float* sp = (r < 40) ? h1 + (size_t)(40 * b + r) * 256
                                       : h0 + (size_t)(4 * b + (r - 40)) * 256;
            f32x4 v = *(const f32x4*)(sp + c4);
            #pragma unroll
            for (int i = 0; i < 4; ++i) sb[i] = f2bf(v[i]);
        }
        st256_4(lAh, r, c4, sb);
    }
    __syncthreads();

    // ---- pass D: acc += lAh @ W1t[:,0:256]^T
    #pragma unroll
    for (int kt = 0; kt < 4; ++kt) {
        const int kbase = kt * 64;
        s16x8 bF[2][4];
        #pragma unroll
        for (int ks = 0; ks < 2; ++ks)
            #pragma unroll
            for (int nn = 0; nn < 4; ++nn)
                bF[ks][nn] = *(const s16x8*)(bp[nn] + kbase + ks * 32);
        #pragma unroll
        for (int ks = 0; ks < 2; ++ks) {
            s16x8 aF[3];
            #pragma unroll
            for (int m = 0; m < 3; ++m)
                aF[m] = ld256_8(lAh, m * 16 + an, kbase + ks * 32 + ak);
            #pragma unroll
            for (int m = 0; m < 3; ++m)
                #pragma unroll
                for (int nn = 0; nn < 4; ++nn)
                    acc[m][nn] = __builtin_amdgcn_mfma_f32_16x16x32_bf16(aF[m], bF[ks][nn], acc[m][nn], 0, 0, 0);
        }
    }
    __syncthreads();   // all lAh reads done -> overlay as lNH

    // ---- epilogue: relu -> bf16 -> lNH (pad rows 44-47 write zeros naturally)
    {
        const int r0 = (lane >> 4) * 4;
        const int c0 = w * 64 + an;
        #pragma unroll
        for (int m = 0; m < 3; ++m)
            #pragma unroll
            for (int nn = 0; nn < 4; ++nn)
                #pragma unroll
                for (int j = 0; j < 4; ++j)
                    st256_1(lAh, m * 16 + r0 + j, c0 + nn * 16, f2bf(fmaxf(acc[m][nn][j], 0.f)));
    }
    __syncthreads();   // lNH complete

    // ---- phase E: mnh[4][256] = mean10(lNH rows 0..39)
    {
        int r = tid >> 6;                     // 0..3
        int c4 = (tid & 63) * 4;
        float a[4] = {0.f, 0.f, 0.f, 0.f};
        #pragma unroll
        for (int j = 0; j < 10; ++j) {
            u16x4 v = ld256_4(lAh, 10 * r + j, c4);
            #pragma unroll
            for (int i = 0; i < 4; ++i) a[i] += bf2f(v[i]);
        }
        u16x4 mb;
        #pragma unroll
        for (int i = 0; i < 4; ++i) mb[i] = f2bf(a[i] * 0.1f);
        st256_4(mnh, r, c4, mb);
    }
    __syncthreads();

    // ---- layer 2: A row an: k<256 -> lNH[40+(an&7)] (rows 44-47 are zero),
    //               k>=256 -> mnh[an&3]; garbage C-rows 4..15 never stored.
    {
        f32x4 acc2[4] = {};
        const u16* bp2[4];
        #pragma unroll
        for (int nn = 0; nn < 4; ++nn)
            bp2[nn] = W2t + (size_t)(w * 64 + nn * 16 + an) * 512 + ak;
        const int rA = 40 + (an & 7);         // in-bounds; zero rows for an 4..7
        const int rM = an & 3;
        #pragma unroll
        for (int kt = 0; kt < 8; ++kt) {
            const int kbase = kt * 64;
            s16x8 bF[2][4];
            #pragma unroll
            for (int ks = 0; ks < 2; ++ks)
                #pragma unroll
                for (int nn = 0; nn < 4; ++nn)
                    bF[ks][nn] = *(const s16x8*)(bp2[nn] + kbase + ks * 32);
            #pragma unroll
            for (int ks = 0; ks < 2; ++ks) {
                const int kk = kbase + ks * 32 + ak;    // slice-uniform side of 256
                s16x8 aF = (kbase + ks * 32 < 256) ? ld256_8(lAh, rA, kk)
                                                   : ld256_8(mnh, rM, kk - 256);
                #pragma unroll
                for (int nn = 0; nn < 4; ++nn)
                    acc2[nn] = __builtin_amdgcn_mfma_f32_16x16x32_bf16(aF, bF[ks][nn], acc2[nn], 0, 0, 0);
            }
        }
        const int r0 = (lane >> 4) * 4;
        const int c0 = w * 64 + an;
        #pragma unroll
        for (int nn = 0; nn < 4; ++nn)
            #pragma unroll
            for (int j = 0; j < 4; ++j) {
                int r = r0 + j;
                if (r < 4)
                    out[(size_t)(4 * b + r) * 256 + c0 + nn * 16] = acc2[nn][j];
            }
    }
}

extern "C" void kernel_launch(void* const* d_in, const int* in_sizes, int n_in,
                              void* d_out, int out_size, void* d_ws, size_t ws_size,
                              hipStream_t stream) {
    const float* h0  = (const float*)d_in[0];
    const float* h1  = (const float*)d_in[1];
    const float* h2  = (const float*)d_in[2];
    const float* w1s = (const float*)d_in[3];
    const float* w1n = (const float*)d_in[4];
    const float* w2s = (const float*)d_in[5];
    const float* w2n = (const float*)d_in[6];

    char* ws = (char*)d_ws;
    u16* W1t = (u16*)ws; ws += (size_t)256 * 512 * 2;
    u16* W2t = (u16*)ws; ws += (size_t)256 * 512 * 2;
    (void)ws_size; (void)in_sizes; (void)n_in; (void)out_size;

    (void)hipFuncSetAttribute((const void*)sage_fused,
                              hipFuncAttributeMaxDynamicSharedMemorySize, K1_LDS);

    conv_w2t<<<64, 256, 0, stream>>>(w1s, w1n, w2s, w2n, W1t, W2t);

    // fused two-layer SAGE: 2500 blocks x 4 output rows, exact cones
    sage_fused<<<2500, 256, K1_LDS, stream>>>(h0, h1, h2, W1t, W2t, (float*)d_out);
}

// Round 15
// 276.808 us; speedup vs baseline: 1.6564x; 1.6564x over previous
//
#include <hip/hip_runtime.h>
#include <stdint.h>

// GraphSAGE on MI355X — FINAL (round-10 verified best, 276.5 µs): fully fused
// two-layer cone kernel + LDS overlay + non-temporal h2 loads.
//
// Dependency cone of output row r is local: h0[r], h1[10r..10r+9],
// h2[100r..100r+99]. Block b owns output rows 4b..4b+3:
//   phase0 : lA[48][512] = { r<40 : bf16(h1[40b+r]) | bf16(mean10 h2-rows) [NT]
//                            r<44 : bf16(h0[4b+r-40]) | bf16(mean10 h1-rows)
//                            else zero }
//   layer1 : lA @ W1t^T (K=512 MFMA) -> sync -> relu -> bf16 lNH[48][256]
//   phase2 : lA2[16][512] := [ lNH[40+r] | mean10(lNH[10r..10r+9]) ], pad zero
//   layer2 : lA2 @ W2t^T -> f32 d_out rows 4b..4b+3
// LDS overlay: lNH/lA2 reuse lA's dead 48 KB -> 3 blocks/CU.
//
// Roofline accounting (12 rounds of A/B evidence): reads are the binding
// resource. Mandatory traffic = 1.137 GB reads (h2 1.024 + h1 0.102 + h0 0.010)
// + 10 MB writes, each byte touched exactly once; intermediates never reach
// HBM. Measured streaming-read ceiling on this part ~4.5 TB/s (pure-stream
// mean kernel 4.76; write-only fillBuffer 6.5). This kernel: ~4.3 TB/s
// effective -> ~90-95% of read ceiling. Failed alternatives: 16-row tiles
// (-37µs L2 dup), gl_lds+vmcnt pipelines (511/450µs, barrier-latency-bound),
// split-K 6blk/CU (458µs), standalone mean kernel (340µs, round-trip cost).

typedef unsigned short u16;
typedef __attribute__((ext_vector_type(4))) float f32x4;
typedef __attribute__((ext_vector_type(8))) short s16x8;
typedef __attribute__((ext_vector_type(4))) unsigned short u16x4;

__device__ inline u16 f2bf(float x) {
    union { float f; uint32_t u; } v; v.f = x;
    uint32_t b = v.u;
    b += 0x7FFFu + ((b >> 16) & 1u);   // round-to-nearest-even
    return (u16)(b >> 16);
}
__device__ inline float bf2f(u16 u) {
    union { uint32_t u; float f; } v; v.u = ((uint32_t)u) << 16;
    return v.f;
}

// Transposed bf16 weight build: dst[n][koff+k] = f2bf(src[k][n]), 64x64 tiles.
__global__ __launch_bounds__(256) void conv_w2t(const float* __restrict__ w1s,
                                                const float* __restrict__ w1n,
                                                const float* __restrict__ w2s,
                                                const float* __restrict__ w2n,
                                                u16* __restrict__ W1t,
                                                u16* __restrict__ W2t) {
    __shared__ u16 t[64][66];
    const int b = blockIdx.x;
    const int mat = b >> 4;
    const int tk = ((b >> 2) & 3) * 64;
    const int tn = (b & 3) * 64;
    const float* src = (mat == 0) ? w1s : (mat == 1) ? w1n : (mat == 2) ? w2s : w2n;
    u16* dst = (mat < 2) ? W1t : W2t;
    const int koff = (mat & 1) * 256;
    const int tid = threadIdx.x;
    const int li = tid >> 6, ln = tid & 63;
    #pragma unroll
    for (int p = 0; p < 16; ++p) {
        int k = p * 4 + li;
        t[k][ln] = f2bf(src[(size_t)(tk + k) * 256 + tn + ln]);
    }
    __syncthreads();
    #pragma unroll
    for (int p = 0; p < 16; ++p) {
        int n = p * 4 + li;
        dst[(size_t)(tn + n) * 512 + koff + tk + ln] = t[ln][n];
    }
}

// ---- swizzled LDS tiles. Row = ROWLEN u16; 16B chunks; phys = chunk ^ (r&7).
__device__ inline void storeA(u16* t, int r, int c, u16x4 v) {      // ROWLEN 512
    int byte = c * 2, chunk = byte >> 4, off = byte & 15;
    *(u16x4*)((char*)(t + (size_t)r * 512) + ((chunk ^ (r & 7)) * 16) + off) = v;
}
__device__ inline s16x8 readA8(const u16* t, int r, int k) {        // 16B, k mult 8
    int chunk = (k * 2) >> 4;
    return *(const s16x8*)((const char*)(t + (size_t)r * 512) + ((chunk ^ (r & 7)) * 16));
}
__device__ inline void storeNH1(u16* t, int r, int c, u16 v) {      // ROWLEN 256
    int byte = c * 2, chunk = byte >> 4, off = byte & 15;
    *(u16*)((char*)(t + (size_t)r * 256) + ((chunk ^ (r & 7)) * 16) + off) = v;
}
__device__ inline u16x4 readNH4(const u16* t, int r, int c) {       // 8B, c mult 4
    int byte = c * 2, chunk = byte >> 4, off = byte & 15;
    return *(const u16x4*)((const char*)(t + (size_t)r * 256) + ((chunk ^ (r & 7)) * 16) + off);
}

__global__ __launch_bounds__(256, 3) void sage_fused(const float* __restrict__ h0,
                                                     const float* __restrict__ h1,
                                                     const float* __restrict__ h2,
                                                     const u16* __restrict__ W1t,
                                                     const u16* __restrict__ W2t,
                                                     float* __restrict__ out) {
    // 48 KB total. lA = [48][512]. After layer-1 K-loop + barrier, lA is dead:
    // overlay lNH[48][256] at [0,24K) and lA2[16][512] at [24K,40K).
    __shared__ __align__(16) u16 buf[48 * 512];
    u16* lA  = buf;
    u16* lNH = buf;              // bytes [0, 24576)
    u16* lA2 = buf + 12288;      // bytes [24576, 40960)

    const int b = blockIdx.x;
    const int tid = threadIdx.x;
    const int lane = tid & 63;
    const int wave = tid >> 6;
    const int an = lane & 15;
    const int ak = (lane >> 4) * 8;

    // ---- phase 0: build lA[48][512]  (48 rows x 64 chunks = 3072; 12/thread)
    #pragma unroll
    for (int p = 0; p < 12; ++p) {
        int chunk = p * 256 + tid;
        int r = chunk >> 6;                   // wave-uniform (64 tids per r step)
        int c4 = (chunk & 63) * 4;
        u16x4 sb = {0, 0, 0, 0}, mb = {0, 0, 0, 0};
        if (r < 44) {
            f32x4 sv;
            f32x4 acc = {0.f, 0.f, 0.f, 0.f};
            if (r < 40) {
                // h2 stream: 1.024 GB, never reused -> NON-TEMPORAL (bypass L2/L3)
                const float* sp = h1 + (size_t)(40 * b + r) * 256;
                const float* np = h2 + (size_t)(400 * b + 10 * r) * 256;
                sv = *(const f32x4*)(sp + c4);
                #pragma unroll
                for (int j = 0; j < 10; ++j)
                    acc += __builtin_nontemporal_load((const f32x4*)(np + (size_t)j * 256 + c4));
            } else {
                // h0 self + h1 neighbors (h1 rows reused within block -> cached)
                int i = r - 40;
                const float* sp = h0 + (size_t)(4 * b + i) * 256;
                const float* np = h1 + (size_t)(40 * b + 10 * i) * 256;
                sv = *(const f32x4*)(sp + c4);
                #pragma unroll
                for (int j = 0; j < 10; ++j)
                    acc += *(const f32x4*)(np + (size_t)j * 256 + c4);
            }
            #pragma unroll
            for (int i = 0; i < 4; ++i) { sb[i] = f2bf(sv[i]); mb[i] = f2bf(acc[i] * 0.1f); }
        }
        storeA(lA, r, c4, sb);
        storeA(lA, r, 256 + c4, mb);
    }
    __syncthreads();

    // ---- layer 1: lA[48][512] @ W1t^T -> (sync) -> relu -> bf16 lNH[48][256]
    {
        f32x4 acc[3][4] = {};
        const u16* bp[4];
        #pragma unroll
        for (int nn = 0; nn < 4; ++nn)
            bp[nn] = W1t + (size_t)(wave * 64 + nn * 16 + an) * 512 + ak;
        for (int kt = 0; kt < 8; ++kt) {
            const int kbase = kt * 64;
            s16x8 bF[2][4];
            #pragma unroll
            for (int ks = 0; ks < 2; ++ks)
                #pragma unroll
                for (int nn = 0; nn < 4; ++nn)
                    bF[ks][nn] = *(const s16x8*)(bp[nn] + kbase + ks * 32);
            #pragma unroll
            for (int ks = 0; ks < 2; ++ks) {
                s16x8 aF[3];
                #pragma unroll
                for (int m = 0; m < 3; ++m)
                    aF[m] = readA8(lA, m * 16 + an, kbase + ks * 32 + ak);
                #pragma unroll
                for (int m = 0; m < 3; ++m)
                    #pragma unroll
                    for (int nn = 0; nn < 4; ++nn)
                        acc[m][nn] = __builtin_amdgcn_mfma_f32_16x16x32_bf16(aF[m], bF[ks][nn], acc[m][nn], 0, 0, 0);
            }
        }
        __syncthreads();   // all waves done READING lA -> overlay region reusable
        // C/D layout: col=lane&15, row=(lane>>4)*4+j  [m89-verified]
        const int r0 = (lane >> 4) * 4;
        const int c0 = wave * 64 + an;
        #pragma unroll
        for (int m = 0; m < 3; ++m)
            #pragma unroll
            for (int nn = 0; nn < 4; ++nn)
                #pragma unroll
                for (int j = 0; j < 4; ++j)
                    storeNH1(lNH, m * 16 + r0 + j, c0 + nn * 16, f2bf(fmaxf(acc[m][nn][j], 0.f)));
    }
    __syncthreads();   // lNH complete

    // ---- phase 2: lA2[16][512] := [ nh0 | mean10(nh1) ], rows 4..15 zero
    #pragma unroll
    for (int p = 0; p < 4; ++p) {
        int chunk = p * 256 + tid;
        int r = chunk >> 6;                 // 0..15
        int c4 = (chunk & 63) * 4;
        u16x4 sb = {0, 0, 0, 0}, mb = {0, 0, 0, 0};
        if (r < 4) {
            sb = readNH4(lNH, 40 + r, c4);
            float a[4] = {0.f, 0.f, 0.f, 0.f};
            #pragma unroll
            for (int j = 0; j < 10; ++j) {
                u16x4 v = readNH4(lNH, 10 * r + j, c4);
                #pragma unroll
                for (int i = 0; i < 4; ++i) a[i] += bf2f(v[i]);
            }
            #pragma unroll
            for (int i = 0; i < 4; ++i) mb[i] = f2bf(a[i] * 0.1f);
        }
        storeA(lA2, r, c4, sb);
        storeA(lA2, r, 256 + c4, mb);
    }
    __syncthreads();

    // ---- layer 2: lA2[16][512] @ W2t^T -> f32 out rows 4b..4b+3
    {
        f32x4 acc[4] = {};
        const u16* bp[4];
        #pragma unroll
        for (int nn = 0; nn < 4; ++nn)
            bp[nn] = W2t + (size_t)(wave * 64 + nn * 16 + an) * 512 + ak;
        for (int kt = 0; kt < 8; ++kt) {
            const int kbase = kt * 64;
            s16x8 bF[2][4];
            #pragma unroll
            for (int ks = 0; ks < 2; ++ks)
                #pragma unroll
                for (int nn = 0; nn < 4; ++nn)
                    bF[ks][nn] = *(const s16x8*)(bp[nn] + kbase + ks * 32);
            #pragma unroll
            for (int ks = 0; ks < 2; ++ks) {
                s16x8 aF = readA8(lA2, an, kbase + ks * 32 + ak);
                #pragma unroll
                for (int nn = 0; nn < 4; ++nn)
                    acc[nn] = __builtin_amdgcn_mfma_f32_16x16x32_bf16(aF, bF[ks][nn], acc[nn], 0, 0, 0);
            }
        }
        const int r0 = (lane >> 4) * 4;
        const int c0 = wave * 64 + an;
        #pragma unroll
        for (int nn = 0; nn < 4; ++nn)
            #pragma unroll
            for (int j = 0; j < 4; ++j) {
                int r = r0 + j;
                if (r < 4)
                    out[(size_t)(4 * b + r) * 256 + c0 + nn * 16] = acc[nn][j];
            }
    }
}

extern "C" void kernel_launch(void* const* d_in, const int* in_sizes, int n_in,
                              void* d_out, int out_size, void* d_ws, size_t ws_size,
                              hipStream_t stream) {
    const float* h0  = (const float*)d_in[0];
    const float* h1  = (const float*)d_in[1];
    const float* h2  = (const float*)d_in[2];
    const float* w1s = (const float*)d_in[3];
    const float* w1n = (const float*)d_in[4];
    const float* w2s = (const float*)d_in[5];
    const float* w2n = (const float*)d_in[6];

    char* ws = (char*)d_ws;
    u16* W1t = (u16*)ws; ws += (size_t)256 * 512 * 2;
    u16* W2t = (u16*)ws; ws += (size_t)256 * 512 * 2;
    (void)ws_size; (void)in_sizes; (void)n_in; (void)out_size;

    conv_w2t<<<64, 256, 0, stream>>>(w1s, w1n, w2s, w2n, W1t, W2t);

    // fully fused two-layer SAGE: 2500 blocks x 4 output rows, exact cones
    sage_fused<<<2500, 256, 0, stream>>>(h0, h1, h2, W1t, W2t, (float*)d_out);
}